// Round 3
// baseline (3360.049 us; speedup 1.0000x reference)
//
#include <hip/hip_runtime.h>

// ---------------------------------------------------------------------------
// BiMamba2 (D_MODEL=1024, D_INNER=2048, NHEADS=32, HEADDIM=64, D_STATE=128,
// D_CONV=4, B=4, L=1024).  Pipeline:
//   ln1 -> (bf16) -> GEMM1 (in-proj, shared both dirs) -> conv+dt (per dir)
//   -> scan (per dir, LDS-pipelined) -> gate+RMS+combine -> GEMM2 -> ln2
// ---------------------------------------------------------------------------

#define BSZ 4
#define SEQ 1024
#define DMODEL 1024
#define DINNER 2048
#define NHEADS 32
#define HEADDIM 64
#define DSTATE 128
#define CONVDIM 2304            // DINNER + 2*DSTATE
#define DPROJ 4384              // 2*DINNER + 2*DSTATE + NHEADS
#define DPROJ_PAD 4480          // padded to multiple of 128
#define NTOK (BSZ*SEQ)          // 4096
#define EPSF 1e-5f

typedef float f32x4 __attribute__((ext_vector_type(4)));
typedef __bf16 bf16x8 __attribute__((ext_vector_type(8)));

__device__ __forceinline__ unsigned short f2bf(float f) {
  unsigned int x = __float_as_uint(f);
  unsigned int r = (x + 0x7fffu + ((x >> 16) & 1u)) >> 16;
  return (unsigned short)r;
}
__device__ __forceinline__ float bf2f(unsigned short u) {
  return __uint_as_float(((unsigned int)u) << 16);
}

__device__ __forceinline__ void async_load16(const void* g, void* l) {
  __builtin_amdgcn_global_load_lds(
      (const __attribute__((address_space(1))) void*)g,
      (__attribute__((address_space(3))) void*)l, 16, 0, 0);
}
__device__ __forceinline__ void async_load4(const void* g, void* l) {
  __builtin_amdgcn_global_load_lds(
      (const __attribute__((address_space(1))) void*)g,
      (__attribute__((address_space(3))) void*)l, 4, 0, 0);
}

// ---------------------------------------------------------------------------
// Prep: weight conversion + lengths
// ---------------------------------------------------------------------------
__global__ void k_convert_w1(const float* __restrict__ w, unsigned short* __restrict__ o) {
  int idx = blockIdx.x * 256 + threadIdx.x;      // 4480*1024 threads
  int row = idx >> 10, col = idx & 1023;
  float v = (row < DPROJ) ? w[(size_t)row * DMODEL + col] : 0.f;
  o[idx] = f2bf(v);
}
__global__ void k_convert_w2(const float* __restrict__ w, unsigned short* __restrict__ o) {
  int idx = blockIdx.x * 256 + threadIdx.x;      // 1024*2048 threads
  o[idx] = f2bf(w[idx]);
}
__global__ void k_lengths(const unsigned char* __restrict__ mask, int* __restrict__ lengths) {
  int b = blockIdx.x, tid = threadIdx.x;
  int cnt = 0;
  for (int k = 0; k < 4; ++k)
    cnt += (mask[(size_t)b * SEQ + tid + k * 256] == 0) ? 1 : 0;
  for (int o = 32; o > 0; o >>= 1) cnt += __shfl_down(cnt, o);
  __shared__ int red[4];
  if ((tid & 63) == 0) red[tid >> 6] = cnt;
  __syncthreads();
  if (tid == 0) lengths[b] = red[0] + red[1] + red[2] + red[3];
}

// ---------------------------------------------------------------------------
// LayerNorm (1024 wide) -> bf16 out
// ---------------------------------------------------------------------------
__global__ __launch_bounds__(256) void k_ln_bf16(const float* __restrict__ in,
                                                 unsigned short* __restrict__ out) {
  int row = blockIdx.x, tid = threadIdx.x;
  float4 v = ((const float4*)(in + (size_t)row * DMODEL))[tid];
  float s = v.x + v.y + v.z + v.w;
  float ss = v.x * v.x + v.y * v.y + v.z * v.z + v.w * v.w;
  for (int o = 32; o > 0; o >>= 1) { s += __shfl_down(s, o); ss += __shfl_down(ss, o); }
  __shared__ float red[8];
  if ((tid & 63) == 0) { red[tid >> 6] = s; red[4 + (tid >> 6)] = ss; }
  __syncthreads();
  s = red[0] + red[1] + red[2] + red[3];
  ss = red[4] + red[5] + red[6] + red[7];
  float mu = s * (1.f / DMODEL);
  float var = ss * (1.f / DMODEL) - mu * mu;
  float rs = rsqrtf(var + EPSF);
  ushort4 o;
  o.x = f2bf((v.x - mu) * rs); o.y = f2bf((v.y - mu) * rs);
  o.z = f2bf((v.z - mu) * rs); o.w = f2bf((v.w - mu) * rs);
  ((ushort4*)(out + (size_t)row * DMODEL))[tid] = o;
}

// LayerNorm (1024 wide) -> fp32 out (final)
__global__ __launch_bounds__(256) void k_ln_f32(const float* __restrict__ in,
                                                float* __restrict__ out) {
  int row = blockIdx.x, tid = threadIdx.x;
  float4 v = ((const float4*)(in + (size_t)row * DMODEL))[tid];
  float s = v.x + v.y + v.z + v.w;
  float ss = v.x * v.x + v.y * v.y + v.z * v.z + v.w * v.w;
  for (int o = 32; o > 0; o >>= 1) { s += __shfl_down(s, o); ss += __shfl_down(ss, o); }
  __shared__ float red[8];
  if ((tid & 63) == 0) { red[tid >> 6] = s; red[4 + (tid >> 6)] = ss; }
  __syncthreads();
  s = red[0] + red[1] + red[2] + red[3];
  ss = red[4] + red[5] + red[6] + red[7];
  float mu = s * (1.f / DMODEL);
  float var = ss * (1.f / DMODEL) - mu * mu;
  float rs = rsqrtf(var + EPSF);
  float4 o;
  o.x = (v.x - mu) * rs; o.y = (v.y - mu) * rs;
  o.z = (v.z - mu) * rs; o.w = (v.w - mu) * rs;
  ((float4*)(out + (size_t)row * DMODEL))[tid] = o;
}

// ---------------------------------------------------------------------------
// bf16 MFMA GEMM (B^T form): C[M,N] = A[M,K] * B[N,K]^T, fp32 out.
// 128x128 block tile, BK=32, 4 waves (2x2), each wave 64x64 via 4x4 MFMA
// 16x16x32 tiles.  global_load_lds width-16 staging (m97 structure).
// ---------------------------------------------------------------------------
__global__ __launch_bounds__(256) void k_gemm_bt(const unsigned short* __restrict__ A,
                                                 const unsigned short* __restrict__ B,
                                                 float* __restrict__ C,
                                                 int K, int lda, int ldb, int ldc) {
  __shared__ unsigned short Asm[128 * 32];
  __shared__ unsigned short Bsm[128 * 32];
  const int tid = threadIdx.x;
  const int lane = tid & 63;
  const int w = tid >> 6;
  const int wm = w >> 1, wn = w & 1;
  const long m0 = (long)blockIdx.x * 128;
  const long n0 = (long)blockIdx.y * 128;

  const int sr = lane >> 2;
  const int sc = (lane & 3) * 8;
  const unsigned short* gA0 = A + (m0 + (w * 2 + 0) * 16 + sr) * (long)lda + sc;
  const unsigned short* gA1 = A + (m0 + (w * 2 + 1) * 16 + sr) * (long)lda + sc;
  const unsigned short* gB0 = B + (n0 + (w * 2 + 0) * 16 + sr) * (long)ldb + sc;
  const unsigned short* gB1 = B + (n0 + (w * 2 + 1) * 16 + sr) * (long)ldb + sc;
  unsigned short* lA0 = Asm + (w * 2 + 0) * 512;
  unsigned short* lA1 = Asm + (w * 2 + 1) * 512;
  unsigned short* lB0 = Bsm + (w * 2 + 0) * 512;
  unsigned short* lB1 = Bsm + (w * 2 + 1) * 512;

  f32x4 acc[4][4] = {};
  const int q8 = (lane >> 4) * 8;
  const int r16 = lane & 15;

  for (int k0 = 0; k0 < K; k0 += 32) {
    async_load16(gA0 + k0, lA0);
    async_load16(gA1 + k0, lA1);
    async_load16(gB0 + k0, lB0);
    async_load16(gB1 + k0, lB1);
    __syncthreads();
    bf16x8 af[4], bfr[4];
#pragma unroll
    for (int i = 0; i < 4; ++i)
      af[i] = *reinterpret_cast<const bf16x8*>(Asm + (wm * 64 + i * 16 + r16) * 32 + q8);
#pragma unroll
    for (int j = 0; j < 4; ++j)
      bfr[j] = *reinterpret_cast<const bf16x8*>(Bsm + (wn * 64 + j * 16 + r16) * 32 + q8);
#pragma unroll
    for (int i = 0; i < 4; ++i)
#pragma unroll
      for (int j = 0; j < 4; ++j)
        acc[i][j] = __builtin_amdgcn_mfma_f32_16x16x32_bf16(af[i], bfr[j], acc[i][j], 0, 0, 0);
    __syncthreads();
  }
  const int q = lane >> 4, cn = lane & 15;
#pragma unroll
  for (int i = 0; i < 4; ++i)
#pragma unroll
    for (int j = 0; j < 4; ++j) {
      long crow = m0 + wm * 64 + i * 16 + q * 4;
      long ccol = n0 + wn * 64 + j * 16 + cn;
#pragma unroll
      for (int r = 0; r < 4; ++r)
        C[(crow + r) * (long)ldc + ccol] = acc[i][j][r];
    }
}

// ---------------------------------------------------------------------------
// Depthwise causal conv (width 4) + SiLU over xBC slice, + dt/dA.
// ---------------------------------------------------------------------------
__global__ __launch_bounds__(256) void k_conv_dt(
    const float* __restrict__ zx,
    const float* __restrict__ cw_f, const float* __restrict__ cb_f,
    const float* __restrict__ cw_r, const float* __restrict__ cb_r,
    const float* __restrict__ dtb_f, const float* __restrict__ al_f,
    const float* __restrict__ dtb_r, const float* __restrict__ al_r,
    const int* __restrict__ lengths,
    float* __restrict__ xBC, float* __restrict__ dtO, float* __restrict__ dAO) {
  const int bx = blockIdx.x;                // (dir*4+b)*1024 + t
  const int t = bx & 1023;
  const int db = bx >> 10;
  const int b = db & 3;
  const int dir = db >> 2;
  const int tid = threadIdx.x;
  const int len = lengths[b];

  const float* cw = dir ? cw_r : cw_f;
  const float* cb = dir ? cb_r : cb_f;
  const float* dtb = dir ? dtb_r : dtb_f;
  const float* al = dir ? al_r : al_f;

  const float* rows[4];
#pragma unroll
  for (int j = 0; j < 4; ++j) {
    int tt = t - 3 + j;
    if (tt < 0) { rows[j] = nullptr; }
    else {
      int s = dir ? ((tt < len) ? (len - 1 - tt) : tt) : tt;
      rows[j] = zx + ((size_t)b * SEQ + s) * DPROJ_PAD;
    }
  }
  float* orow = xBC + ((size_t)db * SEQ + t) * CONVDIM;

#pragma unroll
  for (int k = 0; k < 9; ++k) {             // 2304 = 9*256
    int c = tid + k * 256;
    float4 w4 = *(const float4*)(cw + (size_t)c * 4);
    float acc = cb[c];
    if (rows[0]) acc = fmaf(w4.x, rows[0][DINNER + c], acc);
    if (rows[1]) acc = fmaf(w4.y, rows[1][DINNER + c], acc);
    if (rows[2]) acc = fmaf(w4.z, rows[2][DINNER + c], acc);
    if (rows[3]) acc = fmaf(w4.w, rows[3][DINNER + c], acc);
    float sig = 1.f / (1.f + __expf(-acc));
    orow[c] = acc * sig;
  }
  if (tid < NHEADS) {
    float raw = rows[3][DINNER + CONVDIM + tid] + dtb[tid];
    float dt = (raw > 20.f) ? raw : log1pf(expf(raw));
    float dA = expf(-expf(al[tid]) * dt);
    dtO[((size_t)db * SEQ + t) * NHEADS + tid] = dt;
    dAO[((size_t)db * SEQ + t) * NHEADS + tid] = dA;
  }
}

// ---------------------------------------------------------------------------
// Selective scan, LDS-pipelined.  One block per (dir,b,h,pb): 512 blocks x
// 256 threads.  Thread = (pl = tid>>3, sg = tid&7) owns h[p][sg*16..+16).
// Chunks of 16 timesteps double-buffered in LDS via global_load_lds.
// B/C reads use a rotation swizzle ((j+sg)&3) -> 2-way bank aliasing (free)
// instead of the naive 4-way conflict.  B/C fragments for t+1 are
// prefetched into registers while computing t.  y staged in LDS, flushed
// with coalesced bf16 stores at the start of the next chunk.
// ---------------------------------------------------------------------------
#define TCH 16
#define NCH (SEQ / TCH)

__global__ __launch_bounds__(256) void k_scan(
    const float* __restrict__ xBC, const float* __restrict__ dtb,
    const float* __restrict__ dAb, const float* __restrict__ D_f,
    const float* __restrict__ D_r, unsigned short* __restrict__ y) {
  __shared__ float bc[2][TCH][256];   // B(128)+C(128) per t     32 KB
  __shared__ float xb[2][TCH][32];    // x for this block's 32 p  4 KB
  __shared__ float dd[2][64];         // dt[16],dA[16],junk[32]  512 B
  __shared__ float yb[2][TCH][32];    // y staging                4 KB

  const int bx = blockIdx.x;          // (((dir*4+b)*32+h)*2+pb)
  const int pb = bx & 1;
  const int h = (bx >> 1) & 31;
  const int db = bx >> 6;
  const int dir = db >> 2;
  const int tid = threadIdx.x;
  const int lane = tid & 63;
  const int w = tid >> 6;
  const int sg = tid & 7;
  const int pl = tid >> 3;

  const float Dh = (dir ? D_r : D_f)[h];
  const float* base = xBC + (size_t)db * SEQ * CONVDIM;
  const float* dtp = dtb + (size_t)db * SEQ * NHEADS + h;
  const float* dAp = dAb + (size_t)db * SEQ * NHEADS + h;
  unsigned short* yrow0 = y + (size_t)db * SEQ * DINNER + h * HEADDIM + pb * 32;

  const int xcol = h * HEADDIM + pb * 32 + (lane & 7) * 4;   // for x loads
  const int l2 = lane & 31;                                   // dd dup fold

  f32x4 hs[4];
#pragma unroll
  for (int i = 0; i < 4; ++i) hs[i] = (f32x4){0.f, 0.f, 0.f, 0.f};

  auto issue = [&](int c, int buf) {
    const float* crow = base + (size_t)c * TCH * CONVDIM;
#pragma unroll
    for (int k = 0; k < 4; ++k) {
      int tl = w + k * 4;
      async_load16(crow + (size_t)tl * CONVDIM + DINNER + lane * 4,
                   &bc[buf][tl][0]);
    }
    if (w == 0) {
      async_load16(crow + (size_t)(lane >> 3) * CONVDIM + xcol, &xb[buf][0][0]);
    } else if (w == 1) {
      async_load16(crow + (size_t)(8 + (lane >> 3)) * CONVDIM + xcol, &xb[buf][8][0]);
    } else if (w == 2) {
      const float* g = (l2 < 16) ? (dtp + (size_t)(c * TCH + l2) * NHEADS)
                                 : (dAp + (size_t)(c * TCH + l2 - 16) * NHEADS);
      async_load4(g, &dd[buf][0]);
    }
  };

  auto flushy = [&](int c, int buf) {
    int tl = tid >> 4, pp = (tid & 15) * 2;
    float v0 = yb[buf][tl][pp], v1 = yb[buf][tl][pp + 1];
    ushort2 o; o.x = f2bf(v0); o.y = f2bf(v1);
    *(ushort2*)(yrow0 + (size_t)(c * TCH + tl) * DINNER + pp) = o;
  };

  // rotated (conflict-free) B/C fragment load for one timestep
  auto ldBC = [&](int buf, int tl, f32x4* Bd, f32x4* Cd) {
#pragma unroll
    for (int j = 0; j < 4; ++j) {
      const int jr = (j + sg) & 3;
      Bd[jr] = *(const f32x4*)(&bc[buf][tl][sg * 16 + jr * 4]);
      Cd[jr] = *(const f32x4*)(&bc[buf][tl][128 + sg * 16 + jr * 4]);
    }
  };

  issue(0, 0);
  __syncthreads();

  for (int c = 0; c < NCH; ++c) {
    const int cur = c & 1;
    if (c + 1 < NCH) issue(c + 1, cur ^ 1);
    if (c > 0) flushy(c - 1, cur ^ 1);

    f32x4 Bc_[4], Cc_[4], Bn_[4], Cn_[4];
    ldBC(cur, 0, Bc_, Cc_);
#pragma unroll
    for (int tl = 0; tl < TCH; ++tl) {
      if (tl + 1 < TCH) ldBC(cur, tl + 1, Bn_, Cn_);
      const float dt = dd[cur][tl];
      const float a = dd[cur][16 + tl];
      const float xv = xb[cur][tl][pl];
      const float c1 = dt * xv;
      f32x4 yv = (f32x4){0.f, 0.f, 0.f, 0.f};
#pragma unroll
      for (int j = 0; j < 4; ++j) {
        hs[j] = hs[j] * a + Bc_[j] * c1;   // state update (vector fma)
        yv = yv + hs[j] * Cc_[j];          // y partial  (vector fma)
      }
      float yacc = (yv[0] + yv[1]) + (yv[2] + yv[3]);
      yacc += __shfl_xor(yacc, 1);
      yacc += __shfl_xor(yacc, 2);
      yacc += __shfl_xor(yacc, 4);
      if (sg == 0) yb[cur][tl][pl] = yacc + Dh * xv;
#pragma unroll
      for (int j = 0; j < 4; ++j) { Bc_[j] = Bn_[j]; Cc_[j] = Cn_[j]; }
    }
    __syncthreads();
  }
  flushy(NCH - 1, (NCH - 1) & 1);
}

// ---------------------------------------------------------------------------
// Gate (y * silu(z)) + RMSNorm per direction + average-with-flip -> bf16.
// ---------------------------------------------------------------------------
__global__ __launch_bounds__(256) void k_gate_combine(
    const float* __restrict__ zx, const unsigned short* __restrict__ y,
    const float* __restrict__ nw_f, const float* __restrict__ nw_r,
    const int* __restrict__ lengths, unsigned short* __restrict__ comb) {
  const int bx = blockIdx.x;            // b*SEQ + l
  const int b = bx >> 10, l = bx & 1023;
  const int tid = threadIdx.x;
  const int len = lengths[b];
  const int pos = (l < len) ? (len - 1 - l) : l;
  const float* z = zx + (size_t)bx * DPROJ_PAD;
  const unsigned short* yf = y + ((size_t)b * SEQ + l) * DINNER;
  const unsigned short* yr = y + ((size_t)(BSZ + b) * SEQ + pos) * DINNER;

  float gf[8], gr[8];
  float sf = 0.f, sr = 0.f;
#pragma unroll
  for (int k = 0; k < 8; ++k) {
    int c = tid + k * 256;
    float zz = z[c];
    float sz = zz / (1.f + __expf(-zz));
    float vf = bf2f(yf[c]) * sz;
    float vr = bf2f(yr[c]) * sz;
    gf[k] = vf; gr[k] = vr;
    sf += vf * vf; sr += vr * vr;
  }
  for (int o = 32; o > 0; o >>= 1) { sf += __shfl_down(sf, o); sr += __shfl_down(sr, o); }
  __shared__ float red[8];
  if ((tid & 63) == 0) { red[tid >> 6] = sf; red[4 + (tid >> 6)] = sr; }
  __syncthreads();
  sf = red[0] + red[1] + red[2] + red[3];
  sr = red[4] + red[5] + red[6] + red[7];
  float rf = rsqrtf(sf * (1.f / DINNER) + EPSF);
  float rr = rsqrtf(sr * (1.f / DINNER) + EPSF);
#pragma unroll
  for (int k = 0; k < 8; ++k) {
    int c = tid + k * 256;
    float o = 0.5f * (gf[k] * rf * nw_f[c] + gr[k] * rr * nw_r[c]);
    comb[(size_t)bx * DINNER + c] = f2bf(o);
  }
}

// ---------------------------------------------------------------------------
extern "C" void kernel_launch(void* const* d_in, const int* in_sizes, int n_in,
                              void* d_out, int out_size, void* d_ws, size_t ws_size,
                              hipStream_t stream) {
  const float* hidden      = (const float*)d_in[0];
  const unsigned char* msk = (const unsigned char*)d_in[1];
  const float* in_proj_w   = (const float*)d_in[2];
  const float* out_proj_w  = (const float*)d_in[3];
  const float* conv_w_f    = (const float*)d_in[4];
  const float* conv_b_f    = (const float*)d_in[5];
  const float* dt_bias_f   = (const float*)d_in[6];
  const float* A_log_f     = (const float*)d_in[7];
  const float* D_f         = (const float*)d_in[8];
  const float* norm_w_f    = (const float*)d_in[9];
  const float* conv_w_r    = (const float*)d_in[10];
  const float* conv_b_r    = (const float*)d_in[11];
  const float* dt_bias_r   = (const float*)d_in[12];
  const float* A_log_r     = (const float*)d_in[13];
  const float* D_r         = (const float*)d_in[14];
  const float* norm_w_r    = (const float*)d_in[15];
  float* outF = (float*)d_out;

  char* ws = (char*)d_ws;
  size_t o_w1b  = 0;                         // bf16 [4480][1024]
  size_t o_w2b  = o_w1b  + 9175040;          // bf16 [1024][2048]
  size_t o_hb   = o_w2b  + 4194304;          // bf16 [4096][1024]
  size_t o_zx   = o_hb   + 8388608;          // f32  [4096][4480]
  size_t o_xbc  = o_zx   + 73400320;         // f32  [2][4096][2304]
  size_t o_dt   = o_xbc  + 75497472;         // f32  [2][4096][32]
  size_t o_dA   = o_dt   + 1048576;
  size_t o_y    = o_dA   + 1048576;          // bf16 [2][4096][2048]
  size_t o_comb = o_y    + 33554432;         // bf16 [4096][2048]
  size_t o_outp = o_comb + 16777216;         // f32  [4096][1024]
  size_t o_len  = o_outp + 16777216;         // int  [4]

  unsigned short* W1b  = (unsigned short*)(ws + o_w1b);
  unsigned short* W2b  = (unsigned short*)(ws + o_w2b);
  unsigned short* hb   = (unsigned short*)(ws + o_hb);
  float*          zx   = (float*)(ws + o_zx);
  float*          xBC  = (float*)(ws + o_xbc);
  float*          dtB  = (float*)(ws + o_dt);
  float*          dAB  = (float*)(ws + o_dA);
  unsigned short* yB   = (unsigned short*)(ws + o_y);
  unsigned short* comb = (unsigned short*)(ws + o_comb);
  float*          outp = (float*)(ws + o_outp);
  int*            lens = (int*)(ws + o_len);

  k_convert_w1<<<DPROJ_PAD * DMODEL / 256, 256, 0, stream>>>(in_proj_w, W1b);
  k_convert_w2<<<DMODEL * DINNER / 256, 256, 0, stream>>>(out_proj_w, W2b);
  k_lengths<<<BSZ, 256, 0, stream>>>(msk, lens);

  k_ln_bf16<<<NTOK, 256, 0, stream>>>(hidden, hb);

  k_gemm_bt<<<dim3(NTOK / 128, DPROJ_PAD / 128), 256, 0, stream>>>(
      hb, W1b, zx, DMODEL, DMODEL, DMODEL, DPROJ_PAD);

  k_conv_dt<<<2 * NTOK, 256, 0, stream>>>(
      zx, conv_w_f, conv_b_f, conv_w_r, conv_b_r,
      dt_bias_f, A_log_f, dt_bias_r, A_log_r, lens, xBC, dtB, dAB);

  k_scan<<<512, 256, 0, stream>>>(xBC, dtB, dAB, D_f, D_r, yB);

  k_gate_combine<<<NTOK, 256, 0, stream>>>(zx, yB, norm_w_f, norm_w_r, lens, comb);

  k_gemm_bt<<<dim3(NTOK / 128, DMODEL / 128), 256, 0, stream>>>(
      comb, W2b, outp, DINNER, DINNER, DINNER, DMODEL);

  k_ln_f32<<<NTOK, 256, 0, stream>>>(outp, outF);

  (void)in_sizes; (void)n_in; (void)out_size; (void)ws_size;
}

// Round 5
// 413.187 us; speedup vs baseline: 8.1320x; 8.1320x over previous
//
#include <hip/hip_runtime.h>

// ---------------------------------------------------------------------------
// BiMamba2 (D_MODEL=1024, D_INNER=2048, NHEADS=32, HEADDIM=64, D_STATE=128,
// D_CONV=4, B=4, L=1024).  Pipeline:
//   ln1 -> (bf16) -> GEMM1 (in-proj, shared both dirs) -> conv+dt (per dir)
//   -> chunked MFMA scan (per dir) -> gate+RMS+combine -> GEMM2 -> ln2
// ---------------------------------------------------------------------------

#define BSZ 4
#define SEQ 1024
#define DMODEL 1024
#define DINNER 2048
#define NHEADS 32
#define HEADDIM 64
#define DSTATE 128
#define CONVDIM 2304            // DINNER + 2*DSTATE
#define DPROJ 4384              // 2*DINNER + 2*DSTATE + NHEADS
#define DPROJ_PAD 4480          // padded to multiple of 128
#define NTOK (BSZ*SEQ)          // 4096
#define EPSF 1e-5f
#define CH 32                   // scan chunk length
#define NCHK (SEQ/CH)           // 32 chunks

typedef float f32x4 __attribute__((ext_vector_type(4)));
typedef __bf16 bf16x8 __attribute__((ext_vector_type(8)));

__device__ __forceinline__ unsigned short f2bf(float f) {
  unsigned int x = __float_as_uint(f);
  unsigned int r = (x + 0x7fffu + ((x >> 16) & 1u)) >> 16;
  return (unsigned short)r;
}
__device__ __forceinline__ float bf2f(unsigned short u) {
  return __uint_as_float(((unsigned int)u) << 16);
}

__device__ __forceinline__ void async_load16(const void* g, void* l) {
  __builtin_amdgcn_global_load_lds(
      (const __attribute__((address_space(1))) void*)g,
      (__attribute__((address_space(3))) void*)l, 16, 0, 0);
}

// ---------------------------------------------------------------------------
// Prep: weight conversion + lengths
// ---------------------------------------------------------------------------
__global__ void k_convert_w1(const float* __restrict__ w, unsigned short* __restrict__ o) {
  int idx = blockIdx.x * 256 + threadIdx.x;
  int row = idx >> 10, col = idx & 1023;
  float v = (row < DPROJ) ? w[(size_t)row * DMODEL + col] : 0.f;
  o[idx] = f2bf(v);
}
__global__ void k_convert_w2(const float* __restrict__ w, unsigned short* __restrict__ o) {
  int idx = blockIdx.x * 256 + threadIdx.x;
  o[idx] = f2bf(w[idx]);
}
__global__ void k_lengths(const unsigned char* __restrict__ mask, int* __restrict__ lengths) {
  int b = blockIdx.x, tid = threadIdx.x;
  int cnt = 0;
  for (int k = 0; k < 4; ++k)
    cnt += (mask[(size_t)b * SEQ + tid + k * 256] == 0) ? 1 : 0;
  for (int o = 32; o > 0; o >>= 1) cnt += __shfl_down(cnt, o);
  __shared__ int red[4];
  if ((tid & 63) == 0) red[tid >> 6] = cnt;
  __syncthreads();
  if (tid == 0) lengths[b] = red[0] + red[1] + red[2] + red[3];
}

// ---------------------------------------------------------------------------
// LayerNorm (1024 wide) -> bf16 out
// ---------------------------------------------------------------------------
__global__ __launch_bounds__(256) void k_ln_bf16(const float* __restrict__ in,
                                                 unsigned short* __restrict__ out) {
  int row = blockIdx.x, tid = threadIdx.x;
  float4 v = ((const float4*)(in + (size_t)row * DMODEL))[tid];
  float s = v.x + v.y + v.z + v.w;
  float ss = v.x * v.x + v.y * v.y + v.z * v.z + v.w * v.w;
  for (int o = 32; o > 0; o >>= 1) { s += __shfl_down(s, o); ss += __shfl_down(ss, o); }
  __shared__ float red[8];
  if ((tid & 63) == 0) { red[tid >> 6] = s; red[4 + (tid >> 6)] = ss; }
  __syncthreads();
  s = red[0] + red[1] + red[2] + red[3];
  ss = red[4] + red[5] + red[6] + red[7];
  float mu = s * (1.f / DMODEL);
  float var = ss * (1.f / DMODEL) - mu * mu;
  float rs = rsqrtf(var + EPSF);
  ushort4 o;
  o.x = f2bf((v.x - mu) * rs); o.y = f2bf((v.y - mu) * rs);
  o.z = f2bf((v.z - mu) * rs); o.w = f2bf((v.w - mu) * rs);
  ((ushort4*)(out + (size_t)row * DMODEL))[tid] = o;
}

// LayerNorm (1024 wide) -> fp32 out (final)
__global__ __launch_bounds__(256) void k_ln_f32(const float* __restrict__ in,
                                                float* __restrict__ out) {
  int row = blockIdx.x, tid = threadIdx.x;
  float4 v = ((const float4*)(in + (size_t)row * DMODEL))[tid];
  float s = v.x + v.y + v.z + v.w;
  float ss = v.x * v.x + v.y * v.y + v.z * v.z + v.w * v.w;
  for (int o = 32; o > 0; o >>= 1) { s += __shfl_down(s, o); ss += __shfl_down(ss, o); }
  __shared__ float red[8];
  if ((tid & 63) == 0) { red[tid >> 6] = s; red[4 + (tid >> 6)] = ss; }
  __syncthreads();
  s = red[0] + red[1] + red[2] + red[3];
  ss = red[4] + red[5] + red[6] + red[7];
  float mu = s * (1.f / DMODEL);
  float var = ss * (1.f / DMODEL) - mu * mu;
  float rs = rsqrtf(var + EPSF);
  float4 o;
  o.x = (v.x - mu) * rs; o.y = (v.y - mu) * rs;
  o.z = (v.z - mu) * rs; o.w = (v.w - mu) * rs;
  ((float4*)(out + (size_t)row * DMODEL))[tid] = o;
}

// ---------------------------------------------------------------------------
// bf16 MFMA GEMM (B^T form): C[M,N] = A[M,K] * B[N,K]^T, fp32 out.
// ---------------------------------------------------------------------------
__global__ __launch_bounds__(256) void k_gemm_bt(const unsigned short* __restrict__ A,
                                                 const unsigned short* __restrict__ B,
                                                 float* __restrict__ C,
                                                 int K, int lda, int ldb, int ldc) {
  __shared__ unsigned short Asm[128 * 32];
  __shared__ unsigned short Bsm[128 * 32];
  const int tid = threadIdx.x;
  const int lane = tid & 63;
  const int w = tid >> 6;
  const int wm = w >> 1, wn = w & 1;
  const long m0 = (long)blockIdx.x * 128;
  const long n0 = (long)blockIdx.y * 128;

  const int sr = lane >> 2;
  const int sc = (lane & 3) * 8;
  const unsigned short* gA0 = A + (m0 + (w * 2 + 0) * 16 + sr) * (long)lda + sc;
  const unsigned short* gA1 = A + (m0 + (w * 2 + 1) * 16 + sr) * (long)lda + sc;
  const unsigned short* gB0 = B + (n0 + (w * 2 + 0) * 16 + sr) * (long)ldb + sc;
  const unsigned short* gB1 = B + (n0 + (w * 2 + 1) * 16 + sr) * (long)ldb + sc;
  unsigned short* lA0 = Asm + (w * 2 + 0) * 512;
  unsigned short* lA1 = Asm + (w * 2 + 1) * 512;
  unsigned short* lB0 = Bsm + (w * 2 + 0) * 512;
  unsigned short* lB1 = Bsm + (w * 2 + 1) * 512;

  f32x4 acc[4][4] = {};
  const int q8 = (lane >> 4) * 8;
  const int r16 = lane & 15;

  for (int k0 = 0; k0 < K; k0 += 32) {
    async_load16(gA0 + k0, lA0);
    async_load16(gA1 + k0, lA1);
    async_load16(gB0 + k0, lB0);
    async_load16(gB1 + k0, lB1);
    __syncthreads();
    bf16x8 af[4], bfr[4];
#pragma unroll
    for (int i = 0; i < 4; ++i)
      af[i] = *reinterpret_cast<const bf16x8*>(Asm + (wm * 64 + i * 16 + r16) * 32 + q8);
#pragma unroll
    for (int j = 0; j < 4; ++j)
      bfr[j] = *reinterpret_cast<const bf16x8*>(Bsm + (wn * 64 + j * 16 + r16) * 32 + q8);
#pragma unroll
    for (int i = 0; i < 4; ++i)
#pragma unroll
      for (int j = 0; j < 4; ++j)
        acc[i][j] = __builtin_amdgcn_mfma_f32_16x16x32_bf16(af[i], bfr[j], acc[i][j], 0, 0, 0);
    __syncthreads();
  }
  const int q = lane >> 4, cn = lane & 15;
#pragma unroll
  for (int i = 0; i < 4; ++i)
#pragma unroll
    for (int j = 0; j < 4; ++j) {
      long crow = m0 + wm * 64 + i * 16 + q * 4;
      long ccol = n0 + wn * 64 + j * 16 + cn;
#pragma unroll
      for (int r = 0; r < 4; ++r)
        C[(crow + r) * (long)ldc + ccol] = acc[i][j][r];
    }
}

// ---------------------------------------------------------------------------
// Depthwise causal conv (width 4) + SiLU over xBC slice -> bf16, + dt.
// ---------------------------------------------------------------------------
__global__ __launch_bounds__(256) void k_conv_dt(
    const float* __restrict__ zx,
    const float* __restrict__ cw_f, const float* __restrict__ cb_f,
    const float* __restrict__ cw_r, const float* __restrict__ cb_r,
    const float* __restrict__ dtb_f, const float* __restrict__ dtb_r,
    const int* __restrict__ lengths,
    __bf16* __restrict__ xb, float* __restrict__ dtO) {
  const int bx = blockIdx.x;                // (dir*4+b)*1024 + t
  const int t = bx & 1023;
  const int db = bx >> 10;
  const int b = db & 3;
  const int dir = db >> 2;
  const int tid = threadIdx.x;
  const int len = lengths[b];

  const float* cw = dir ? cw_r : cw_f;
  const float* cb = dir ? cb_r : cb_f;
  const float* dtb = dir ? dtb_r : dtb_f;

  const float* rows[4];
#pragma unroll
  for (int j = 0; j < 4; ++j) {
    int tt = t - 3 + j;
    if (tt < 0) { rows[j] = nullptr; }
    else {
      int s = dir ? ((tt < len) ? (len - 1 - tt) : tt) : tt;
      rows[j] = zx + ((size_t)b * SEQ + s) * DPROJ_PAD;
    }
  }
  __bf16* orow = xb + ((size_t)db * SEQ + t) * CONVDIM;

#pragma unroll
  for (int k = 0; k < 9; ++k) {             // 2304 = 9*256
    int c = tid + k * 256;
    float4 w4 = *(const float4*)(cw + (size_t)c * 4);
    float acc = cb[c];
    if (rows[0]) acc = fmaf(w4.x, rows[0][DINNER + c], acc);
    if (rows[1]) acc = fmaf(w4.y, rows[1][DINNER + c], acc);
    if (rows[2]) acc = fmaf(w4.z, rows[2][DINNER + c], acc);
    if (rows[3]) acc = fmaf(w4.w, rows[3][DINNER + c], acc);
    float sig = 1.f / (1.f + __expf(-acc));
    orow[c] = (__bf16)(acc * sig);
  }
  if (tid < NHEADS) {
    float raw = rows[3][DINNER + CONVDIM + tid] + dtb[tid];
    float dt = (raw > 20.f) ? raw : log1pf(expf(raw));
    dtO[((size_t)db * SEQ + t) * NHEADS + tid] = dt;
  }
}

// ---------------------------------------------------------------------------
// Chunked MFMA selective scan.  One block per (dir,b,h): 256 blocks x 256.
// Per chunk (T=32):  G = C@B^T (MFMA);  S = G .* causal-decay (bf16 via LDS);
//   y^T = X^T@S^T + (H@C^T).*P_t + D*x  (MFMA);  H = e^{cd31} H + (X.*W)^T@B.
// All matmuls use the validated row-frag convention D = A[M,K]*B[N,K]^T.
// H carried in fp32 accumulators; bf16 LDS copy feeds next chunk's y_inter.
// ---------------------------------------------------------------------------
__global__ __launch_bounds__(256) void k_scan(
    const __bf16* __restrict__ xb, const float* __restrict__ dtb,
    const float* __restrict__ A_log_f, const float* __restrict__ A_log_r,
    const float* __restrict__ D_f, const float* __restrict__ D_r,
    unsigned short* __restrict__ y) {
  __shared__ __bf16 Braw[32 * 136];   // B chunk  [s][n], stride 136
  __shared__ __bf16 Craw[32 * 136];   // C chunk  [t][n]
  __shared__ __bf16 BTl [128 * 40];   // B^T      [n][s], stride 40
  __shared__ __bf16 XTl [64 * 40];    // X^T      [p][s]
  __shared__ __bf16 SL  [32 * 40];    // masked S [t][s] (identical per wave)
  __shared__ __bf16 HL  [4][16 * 136];// per-wave H copy [p][n]
  __shared__ __bf16 yO  [32 * 72];    // y chunk  [t][p], stride 72
  __shared__ float dd_dt[32], dd_cd[32], dd_W[32], dd_P[32];

  const int bx = blockIdx.x;          // db*32 + h
  const int h  = bx & 31;
  const int db = bx >> 5;
  const int dir = db >> 2;
  const int tid = threadIdx.x;
  const int lane = tid & 63;
  const int w = tid >> 6;
  const int l15 = lane & 15;
  const int q = lane >> 4;
  const int q8 = q * 8;

  const float Dh = (dir ? D_r : D_f)[h];
  const float Ah = -__expf((dir ? A_log_r : A_log_f)[h]);

  const __bf16* xbase = xb + (size_t)db * SEQ * CONVDIM;
  const float* dtp = dtb + (size_t)db * SEQ * NHEADS + h;
  unsigned short* ybase = y + (size_t)db * SEQ * DINNER + h * HEADDIM;

  // zero own HL slice; H accumulator in registers
  for (int i = lane; i < 16 * 136; i += 64) HL[w][i] = (__bf16)0.f;
  f32x4 accH[8];
#pragma unroll
  for (int i = 0; i < 8; ++i) accH[i] = (f32x4){0.f, 0.f, 0.f, 0.f};

  auto stage = [&](int c) {
    const int s0 = c * CH;
    const __bf16* xr = xbase + (size_t)s0 * CONVDIM;
    {   // B,C row-major copies: 16 cols per thread (2x bf16x8 each)
      int sB = tid >> 3, c0 = (tid & 7) * 16;
      const __bf16* src = xr + (size_t)sB * CONVDIM + DINNER;
      bf16x8 vB0 = *(const bf16x8*)(src + c0);
      bf16x8 vB1 = *(const bf16x8*)(src + c0 + 8);
      bf16x8 vC0 = *(const bf16x8*)(src + 128 + c0);
      bf16x8 vC1 = *(const bf16x8*)(src + 128 + c0 + 8);
      *(bf16x8*)&Braw[sB * 136 + c0] = vB0;
      *(bf16x8*)&Braw[sB * 136 + c0 + 8] = vB1;
      *(bf16x8*)&Craw[sB * 136 + c0] = vC0;
      *(bf16x8*)&Craw[sB * 136 + c0 + 8] = vC1;
    }
    {   // X^T and B^T scatter builds
      int sX = tid & 31, g = tid >> 5;
      int p8 = g * 8;
      bf16x8 vx = *(const bf16x8*)(xr + (size_t)sX * CONVDIM + h * HEADDIM + p8);
#pragma unroll
      for (int i = 0; i < 8; ++i) XTl[(p8 + i) * 40 + sX] = vx[i];
      int n16 = g * 16;
      bf16x8 v0 = *(const bf16x8*)(xr + (size_t)sX * CONVDIM + DINNER + n16);
      bf16x8 v1 = *(const bf16x8*)(xr + (size_t)sX * CONVDIM + DINNER + n16 + 8);
#pragma unroll
      for (int i = 0; i < 8; ++i) BTl[(n16 + i) * 40 + sX] = v0[i];
#pragma unroll
      for (int i = 0; i < 8; ++i) BTl[(n16 + 8 + i) * 40 + sX] = v1[i];
    }
    if (w == 0) {   // dt gather + inclusive prefix + decay tables
      float dtv = (lane < 32) ? dtp[(size_t)(s0 + lane) * NHEADS] : 0.f;
      float cum = dtv;
#pragma unroll
      for (int d = 1; d < 32; d <<= 1) {
        float v2 = __shfl_up(cum, d);
        if ((lane & 31) >= d) cum += v2;
      }
      float cum31 = __shfl(cum, 31);
      if (lane < 32) {
        dd_dt[lane] = dtv;
        dd_cd[lane] = Ah * cum;
        dd_W[lane]  = dtv * __expf(Ah * (cum31 - cum));
        dd_P[lane]  = __expf(Ah * cum);
      }
    }
  };

  stage(0);
  __syncthreads();

  for (int c = 0; c < NCHK; ++c) {
    // ---- operand frags (row-major b128 reads) ----
    bf16x8 Cf[2][4], Bf[2][4];
#pragma unroll
    for (int tt = 0; tt < 2; ++tt)
#pragma unroll
      for (int kk = 0; kk < 4; ++kk) {
        Cf[tt][kk] = *(const bf16x8*)&Craw[(l15 + tt * 16) * 136 + kk * 32 + q8];
        Bf[tt][kk] = *(const bf16x8*)&Braw[(l15 + tt * 16) * 136 + kk * 32 + q8];
      }
    // ---- G = C @ B^T (32x32, K=128) ----
    f32x4 G00 = {}, G01 = {}, G10 = {}, G11 = {};
#pragma unroll
    for (int kk = 0; kk < 4; ++kk) {
      G00 = __builtin_amdgcn_mfma_f32_16x16x32_bf16(Cf[0][kk], Bf[0][kk], G00, 0, 0, 0);
      G01 = __builtin_amdgcn_mfma_f32_16x16x32_bf16(Cf[0][kk], Bf[1][kk], G01, 0, 0, 0);
      G10 = __builtin_amdgcn_mfma_f32_16x16x32_bf16(Cf[1][kk], Bf[0][kk], G10, 0, 0, 0);
      G11 = __builtin_amdgcn_mfma_f32_16x16x32_bf16(Cf[1][kk], Bf[1][kk], G11, 0, 0, 0);
    }
    // ---- causal decay mask -> SL[t][s] (bf16) ----
    {
      float scd0 = dd_cd[l15],      sdt0 = dd_dt[l15];
      float scd1 = dd_cd[16 + l15], sdt1 = dd_dt[16 + l15];
#pragma unroll
      for (int r = 0; r < 4; ++r) {
        int t0 = q * 4 + r;
        float cdt0 = dd_cd[t0], cdt1 = dd_cd[16 + t0];
        float v00 = (t0 >= l15) ? G00[r] * sdt0 * __expf(cdt0 - scd0) : 0.f;
        float v10 = G10[r] * sdt0 * __expf(cdt1 - scd0);
        float v11 = (t0 >= l15) ? G11[r] * sdt1 * __expf(cdt1 - scd1) : 0.f;
        SL[t0 * 40 + l15]             = (__bf16)v00;
        SL[t0 * 40 + 16 + l15]        = (__bf16)0.f;   // strictly upper tile
        SL[(16 + t0) * 40 + l15]      = (__bf16)v10;
        SL[(16 + t0) * 40 + 16 + l15] = (__bf16)v11;
      }
    }
    // ---- y_intra: y^T[p][t] = X^T @ S^T ----
    f32x4 accy0 = {}, accy1 = {};
    bf16x8 xt = *(const bf16x8*)&XTl[(w * 16 + l15) * 40 + q8];
    {
      bf16x8 S0 = *(const bf16x8*)&SL[l15 * 40 + q8];
      bf16x8 S1 = *(const bf16x8*)&SL[(16 + l15) * 40 + q8];
      accy0 = __builtin_amdgcn_mfma_f32_16x16x32_bf16(xt, S0, accy0, 0, 0, 0);
      accy1 = __builtin_amdgcn_mfma_f32_16x16x32_bf16(xt, S1, accy1, 0, 0, 0);
    }
    // ---- y_inter: (H @ C^T) .* P_t ----
    {
      f32x4 ai0 = {}, ai1 = {};
#pragma unroll
      for (int nw = 0; nw < 4; ++nw) {
        bf16x8 Hf = *(const bf16x8*)&HL[w][l15 * 136 + nw * 32 + q8];
        ai0 = __builtin_amdgcn_mfma_f32_16x16x32_bf16(Hf, Cf[0][nw], ai0, 0, 0, 0);
        ai1 = __builtin_amdgcn_mfma_f32_16x16x32_bf16(Hf, Cf[1][nw], ai1, 0, 0, 0);
      }
      float P0 = dd_P[l15], P1 = dd_P[16 + l15];
      accy0 = accy0 + ai0 * P0;
      accy1 = accy1 + ai1 * P1;
    }
    // ---- H update: H = atot*H + (X.*W)^T @ B ----
    {
      float atot = dd_P[31];
      f32x4 W0 = *(const f32x4*)&dd_W[q8];
      f32x4 W1 = *(const f32x4*)&dd_W[q8 + 4];
      bf16x8 xw;
#pragma unroll
      for (int j = 0; j < 4; ++j) {
        xw[j]     = (__bf16)((float)xt[j] * W0[j]);
        xw[4 + j] = (__bf16)((float)xt[4 + j] * W1[j]);
      }
#pragma unroll
      for (int nt = 0; nt < 8; ++nt) {
        bf16x8 Btf = *(const bf16x8*)&BTl[(l15 + nt * 16) * 40 + q8];
        accH[nt] = accH[nt] * atot;
        accH[nt] = __builtin_amdgcn_mfma_f32_16x16x32_bf16(xw, Btf, accH[nt], 0, 0, 0);
      }
      // bf16 copy for next chunk's y_inter (wave-private, no barrier needed)
#pragma unroll
      for (int nt = 0; nt < 8; ++nt)
#pragma unroll
        for (int r = 0; r < 4; ++r)
          HL[w][(q * 4 + r) * 136 + nt * 16 + l15] = (__bf16)accH[nt][r];
    }
    // ---- epilogue: + D*x, write yO[t][p] ----
#pragma unroll
    for (int r = 0; r < 4; ++r) {
      int pl = w * 16 + q * 4 + r;
      float x0 = (float)XTl[pl * 40 + l15];
      float x1 = (float)XTl[pl * 40 + 16 + l15];
      yO[l15 * 72 + pl]        = (__bf16)(accy0[r] + Dh * x0);
      yO[(16 + l15) * 72 + pl] = (__bf16)(accy1[r] + Dh * x1);
    }
    __syncthreads();
    if (c + 1 < NCHK) stage(c + 1);
    {   // coalesced y store of chunk c
      int t = tid >> 3, p8 = (tid & 7) * 8;
      bf16x8 vy = *(const bf16x8*)&yO[t * 72 + p8];
      *(bf16x8*)(ybase + (size_t)(c * CH + t) * DINNER + p8) = vy;
    }
    __syncthreads();
  }
}

// ---------------------------------------------------------------------------
// Gate (y * silu(z)) + RMSNorm per direction + average-with-flip -> bf16.
// ---------------------------------------------------------------------------
__global__ __launch_bounds__(256) void k_gate_combine(
    const float* __restrict__ zx, const unsigned short* __restrict__ y,
    const float* __restrict__ nw_f, const float* __restrict__ nw_r,
    const int* __restrict__ lengths, unsigned short* __restrict__ comb) {
  const int bx = blockIdx.x;            // b*SEQ + l
  const int b = bx >> 10, l = bx & 1023;
  const int tid = threadIdx.x;
  const int len = lengths[b];
  const int pos = (l < len) ? (len - 1 - l) : l;
  const float* z = zx + (size_t)bx * DPROJ_PAD;
  const unsigned short* yf = y + ((size_t)b * SEQ + l) * DINNER;
  const unsigned short* yr = y + ((size_t)(BSZ + b) * SEQ + pos) * DINNER;

  float gf[8], gr[8];
  float sf = 0.f, sr = 0.f;
#pragma unroll
  for (int k = 0; k < 8; ++k) {
    int c = tid + k * 256;
    float zz = z[c];
    float sz = zz / (1.f + __expf(-zz));
    float vf = bf2f(yf[c]) * sz;
    float vr = bf2f(yr[c]) * sz;
    gf[k] = vf; gr[k] = vr;
    sf += vf * vf; sr += vr * vr;
  }
  for (int o = 32; o > 0; o >>= 1) { sf += __shfl_down(sf, o); sr += __shfl_down(sr, o); }
  __shared__ float red[8];
  if ((tid & 63) == 0) { red[tid >> 6] = sf; red[4 + (tid >> 6)] = sr; }
  __syncthreads();
  sf = red[0] + red[1] + red[2] + red[3];
  sr = red[4] + red[5] + red[6] + red[7];
  float rf = rsqrtf(sf * (1.f / DINNER) + EPSF);
  float rr = rsqrtf(sr * (1.f / DINNER) + EPSF);
#pragma unroll
  for (int k = 0; k < 8; ++k) {
    int c = tid + k * 256;
    float o = 0.5f * (gf[k] * rf * nw_f[c] + gr[k] * rr * nw_r[c]);
    comb[(size_t)bx * DINNER + c] = f2bf(o);
  }
}

// ---------------------------------------------------------------------------
extern "C" void kernel_launch(void* const* d_in, const int* in_sizes, int n_in,
                              void* d_out, int out_size, void* d_ws, size_t ws_size,
                              hipStream_t stream) {
  const float* hidden      = (const float*)d_in[0];
  const unsigned char* msk = (const unsigned char*)d_in[1];
  const float* in_proj_w   = (const float*)d_in[2];
  const float* out_proj_w  = (const float*)d_in[3];
  const float* conv_w_f    = (const float*)d_in[4];
  const float* conv_b_f    = (const float*)d_in[5];
  const float* dt_bias_f   = (const float*)d_in[6];
  const float* A_log_f     = (const float*)d_in[7];
  const float* D_f         = (const float*)d_in[8];
  const float* norm_w_f    = (const float*)d_in[9];
  const float* conv_w_r    = (const float*)d_in[10];
  const float* conv_b_r    = (const float*)d_in[11];
  const float* dt_bias_r   = (const float*)d_in[12];
  const float* A_log_r     = (const float*)d_in[13];
  const float* D_r         = (const float*)d_in[14];
  const float* norm_w_r    = (const float*)d_in[15];
  float* outF = (float*)d_out;

  char* ws = (char*)d_ws;
  size_t o_w1b  = 0;                         // bf16 [4480][1024]
  size_t o_w2b  = o_w1b  + 9175040;          // bf16 [1024][2048]
  size_t o_hb   = o_w2b  + 4194304;          // bf16 [4096][1024]
  size_t o_zx   = o_hb   + 8388608;          // f32  [4096][4480]
  size_t o_xb   = o_zx   + 73400320;         // bf16 [2][4096][2304]
  size_t o_dt   = o_xb   + 37748736;         // f32  [2][4096][32]
  size_t o_y    = o_dt   + 1048576;          // bf16 [2][4096][2048]
  size_t o_comb = o_y    + 33554432;         // bf16 [4096][2048]
  size_t o_outp = o_comb + 16777216;         // f32  [4096][1024]
  size_t o_len  = o_outp + 16777216;         // int  [4]

  unsigned short* W1b  = (unsigned short*)(ws + o_w1b);
  unsigned short* W2b  = (unsigned short*)(ws + o_w2b);
  unsigned short* hb   = (unsigned short*)(ws + o_hb);
  float*          zx   = (float*)(ws + o_zx);
  __bf16*         xb   = (__bf16*)(ws + o_xb);
  float*          dtB  = (float*)(ws + o_dt);
  unsigned short* yB   = (unsigned short*)(ws + o_y);
  unsigned short* comb = (unsigned short*)(ws + o_comb);
  float*          outp = (float*)(ws + o_outp);
  int*            lens = (int*)(ws + o_len);

  k_convert_w1<<<DPROJ_PAD * DMODEL / 256, 256, 0, stream>>>(in_proj_w, W1b);
  k_convert_w2<<<DMODEL * DINNER / 256, 256, 0, stream>>>(out_proj_w, W2b);
  k_lengths<<<BSZ, 256, 0, stream>>>(msk, lens);

  k_ln_bf16<<<NTOK, 256, 0, stream>>>(hidden, hb);

  k_gemm_bt<<<dim3(NTOK / 128, DPROJ_PAD / 128), 256, 0, stream>>>(
      hb, W1b, zx, DMODEL, DMODEL, DMODEL, DPROJ_PAD);

  k_conv_dt<<<2 * NTOK, 256, 0, stream>>>(
      zx, conv_w_f, conv_b_f, conv_w_r, conv_b_r,
      dt_bias_f, dt_bias_r, lens, xb, dtB);

  k_scan<<<2 * BSZ * NHEADS, 256, 0, stream>>>(
      xb, dtB, A_log_f, A_log_r, D_f, D_r, yB);

  k_gate_combine<<<NTOK, 256, 0, stream>>>(zx, yB, norm_w_f, norm_w_r, lens, comb);

  k_gemm_bt<<<dim3(NTOK / 128, DMODEL / 128), 256, 0, stream>>>(
      comb, W2b, outp, DINNER, DINNER, DINNER, DMODEL);

  k_ln_f32<<<NTOK, 256, 0, stream>>>(outp, outF);

  (void)in_sizes; (void)n_in; (void)out_size; (void)ws_size;
}